// Round 1
// baseline (344.241 us; speedup 1.0000x reference)
//
#include <hip/hip_runtime.h>
#include <hip/hip_bf16.h>

typedef __attribute__((ext_vector_type(8))) __bf16 bf16x8;
typedef __attribute__((ext_vector_type(4))) __bf16 bf16x4;
typedef __attribute__((ext_vector_type(4))) float f32x4;

#define BDIM 2
#define TSEQ 2048
#define CDIM 2048
#define NH 16
#define NKV 4
#define HD 128
#define WIN 512

// ---------------------------------------------------------------------------
// RMSNorm: x (f32 [4096][2048]) -> xn (bf16), one block per row
// ---------------------------------------------------------------------------
__global__ __launch_bounds__(256) void k_rmsnorm(const float* __restrict__ x,
                                                 const float* __restrict__ w,
                                                 __bf16* __restrict__ xn) {
  __shared__ float red[4];
  const int row = blockIdx.x;
  const int tid = threadIdx.x;
  const float* xr = x + (size_t)row * CDIM;
  f32x4 v0 = *reinterpret_cast<const f32x4*>(&xr[tid * 8]);
  f32x4 v1 = *reinterpret_cast<const f32x4*>(&xr[tid * 8 + 4]);
  float s = v0[0] * v0[0] + v0[1] * v0[1] + v0[2] * v0[2] + v0[3] * v0[3] +
            v1[0] * v1[0] + v1[1] * v1[1] + v1[2] * v1[2] + v1[3] * v1[3];
#pragma unroll
  for (int off = 32; off > 0; off >>= 1) s += __shfl_down(s, off, 64);
  if ((tid & 63) == 0) red[tid >> 6] = s;
  __syncthreads();
  float tot = red[0] + red[1] + red[2] + red[3];
  float nrm = rsqrtf(tot * (1.0f / CDIM) + 1e-6f);
  const float* wp = w + tid * 8;
  bf16x8 o;
  o[0] = (__bf16)(v0[0] * nrm * wp[0]);
  o[1] = (__bf16)(v0[1] * nrm * wp[1]);
  o[2] = (__bf16)(v0[2] * nrm * wp[2]);
  o[3] = (__bf16)(v0[3] * nrm * wp[3]);
  o[4] = (__bf16)(v1[0] * nrm * wp[4]);
  o[5] = (__bf16)(v1[1] * nrm * wp[5]);
  o[6] = (__bf16)(v1[2] * nrm * wp[6]);
  o[7] = (__bf16)(v1[3] * nrm * wp[7]);
  *reinterpret_cast<bf16x8*>(&xn[(size_t)row * CDIM + tid * 8]) = o;
}

// ---------------------------------------------------------------------------
// Weight transpose+convert: W f32 [K=2048][N] -> Wt bf16 [N][2048]
// 64x64 tile per block, 256 threads
// ---------------------------------------------------------------------------
__global__ __launch_bounds__(256) void k_wtrans(const float* __restrict__ W,
                                                __bf16* __restrict__ Wt, int N) {
  __shared__ float lt[64][65];
  const int tid = threadIdx.x;
  const int n0 = blockIdx.x * 64, k0 = blockIdx.y * 64;
  const int tr = tid >> 4, tc = tid & 15;
#pragma unroll
  for (int i = 0; i < 4; ++i) {
    int kr = tr + i * 16;
    f32x4 vv = *reinterpret_cast<const f32x4*>(&W[(size_t)(k0 + kr) * N + n0 + tc * 4]);
    lt[kr][tc * 4 + 0] = vv[0];
    lt[kr][tc * 4 + 1] = vv[1];
    lt[kr][tc * 4 + 2] = vv[2];
    lt[kr][tc * 4 + 3] = vv[3];
  }
  __syncthreads();
#pragma unroll
  for (int i = 0; i < 4; ++i) {
    int nr = tr + i * 16;
    int kc = tc * 4;
    bf16x4 o;
    o[0] = (__bf16)lt[kc + 0][nr];
    o[1] = (__bf16)lt[kc + 1][nr];
    o[2] = (__bf16)lt[kc + 2][nr];
    o[3] = (__bf16)lt[kc + 3][nr];
    *reinterpret_cast<bf16x4*>(&Wt[(size_t)(n0 + nr) * 2048 + k0 + kc]) = o;
  }
}

// ---------------------------------------------------------------------------
// RoPE in-place on Q (bf16 [B][16][T][128]) and K (bf16 [B][4][T][128]).
// One 64-lane wave per (b, t, head); 4 waves per block.
// ---------------------------------------------------------------------------
__global__ __launch_bounds__(256) void k_rope(__bf16* __restrict__ Q,
                                              __bf16* __restrict__ K,
                                              const float* __restrict__ rc,
                                              const float* __restrict__ rs) {
  int g = blockIdx.x * 4 + (threadIdx.x >> 6);
  int lane = threadIdx.x & 63;
  int b = g / (TSEQ * (NH + NKV));
  int rem = g % (TSEQ * (NH + NKV));
  int t = rem / (NH + NKV);
  int hh = rem % (NH + NKV);
  __bf16* base;
  if (hh < NH)
    base = Q + (((size_t)(b * NH + hh)) * TSEQ + t) * HD;
  else
    base = K + (((size_t)(b * NKV + (hh - NH))) * TSEQ + t) * HD;
  float x1 = (float)base[lane];
  float x2 = (float)base[lane + 64];
  float c = rc[t * 64 + lane];
  float s = rs[t * 64 + lane];
  base[lane] = (__bf16)(x1 * c - x2 * s);
  base[lane + 64] = (__bf16)(x2 * c + x1 * s);
}

// ---------------------------------------------------------------------------
// GEMM QKV: C[4096][3072] = xn[4096][2048] @ [wq|wk|wv]; B supplied transposed
// (bf16 [N][K]).  128x128 tile, BK=32, 4 waves (2x2), 16x16x32 MFMA.
// Epilogue scatters into Q/K/V (B,H,T,D) bf16.
// ---------------------------------------------------------------------------
__global__ __launch_bounds__(256) void k_gemm_qkv(
    const __bf16* __restrict__ xn, const __bf16* __restrict__ wqT,
    const __bf16* __restrict__ wkT, const __bf16* __restrict__ wvT,
    __bf16* __restrict__ Q, __bf16* __restrict__ K, __bf16* __restrict__ V) {
  __shared__ __align__(16) __bf16 lA[128][40];
  __shared__ __align__(16) __bf16 lB[128][40];
  const int tid = threadIdx.x;
  const int lane = tid & 63;
  const int wid = tid >> 6;
  const int wrow = (wid >> 1) * 64, wcol = (wid & 1) * 64;
  const int l16 = lane & 15, lhi = lane >> 4;
  const int m0 = blockIdx.y * 128;
  const int n0 = blockIdx.x * 128;
  const __bf16* wt;
  int nrel;
  if (n0 < 2048) { wt = wqT; nrel = n0; }
  else if (n0 < 2560) { wt = wkT; nrel = n0 - 2048; }
  else { wt = wvT; nrel = n0 - 2560; }

  f32x4 acc[4][4] = {};

  for (int k0 = 0; k0 < CDIM; k0 += 32) {
#pragma unroll
    for (int i = 0; i < 2; ++i) {
      int slot = tid + i * 256;
      int r = slot >> 2, c = (slot & 3) * 8;
      *reinterpret_cast<bf16x8*>(&lA[r][c]) =
          *reinterpret_cast<const bf16x8*>(&xn[(size_t)(m0 + r) * CDIM + k0 + c]);
      *reinterpret_cast<bf16x8*>(&lB[r][c]) =
          *reinterpret_cast<const bf16x8*>(&wt[(size_t)(nrel + r) * CDIM + k0 + c]);
    }
    __syncthreads();
    bf16x8 a[4], b[4];
#pragma unroll
    for (int mi = 0; mi < 4; ++mi)
      a[mi] = *reinterpret_cast<const bf16x8*>(&lA[wrow + mi * 16 + l16][lhi * 8]);
#pragma unroll
    for (int ni = 0; ni < 4; ++ni)
      b[ni] = *reinterpret_cast<const bf16x8*>(&lB[wcol + ni * 16 + l16][lhi * 8]);
#pragma unroll
    for (int mi = 0; mi < 4; ++mi)
#pragma unroll
      for (int ni = 0; ni < 4; ++ni)
        acc[mi][ni] = __builtin_amdgcn_mfma_f32_16x16x32_bf16(a[mi], b[ni], acc[mi][ni], 0, 0, 0);
    __syncthreads();
  }

#pragma unroll
  for (int mi = 0; mi < 4; ++mi) {
#pragma unroll
    for (int ni = 0; ni < 4; ++ni) {
#pragma unroll
      for (int r = 0; r < 4; ++r) {
        int row = m0 + wrow + mi * 16 + lhi * 4 + r;
        int col = n0 + wcol + ni * 16 + l16;
        int bb = row >> 11, t = row & 2047;
        __bf16 hv = (__bf16)acc[mi][ni][r];
        if (col < 2048) {
          int h = col >> 7, d = col & 127;
          Q[(((size_t)(bb * NH + h)) * TSEQ + t) * HD + d] = hv;
        } else if (col < 2560) {
          int h = (col - 2048) >> 7, d = col & 127;
          K[(((size_t)(bb * NKV + h)) * TSEQ + t) * HD + d] = hv;
        } else {
          int h = (col - 2560) >> 7, d = col & 127;
          V[(((size_t)(bb * NKV + h)) * TSEQ + t) * HD + d] = hv;
        }
      }
    }
  }
}

// ---------------------------------------------------------------------------
// Flash attention, sliding window 512, causal, GQA 16/4.
// Block: (b,h, 64 q rows); 4 waves x 16 q rows. s-tiles of 32.
// ---------------------------------------------------------------------------
__global__ __launch_bounds__(256) void k_attn(const __bf16* __restrict__ Q,
                                              const __bf16* __restrict__ K,
                                              const __bf16* __restrict__ V,
                                              __bf16* __restrict__ Aout) {
  __shared__ __align__(16) __bf16 lK[32][136];
  __shared__ __align__(16) __bf16 lVt[128][40];
  __shared__ __align__(16) __bf16 lP[4][16][40];

  const int tid = threadIdx.x, lane = tid & 63, wid = tid >> 6;
  const int l16 = lane & 15, lhi = lane >> 4;
  const int bh = blockIdx.y;
  const int b = bh >> 4, h = bh & 15;
  const int kvh = h >> 2;
  const int q0 = blockIdx.x * 64;
  const int qw = q0 + wid * 16;

  const __bf16* Qb = Q + (size_t)bh * TSEQ * HD;
  const __bf16* Kb = K + (size_t)(b * NKV + kvh) * TSEQ * HD;
  const __bf16* Vb = V + (size_t)(b * NKV + kvh) * TSEQ * HD;

  bf16x8 aq[4];
#pragma unroll
  for (int dblk = 0; dblk < 4; ++dblk)
    aq[dblk] = *reinterpret_cast<const bf16x8*>(&Qb[(size_t)(qw + l16) * HD + dblk * 32 + lhi * 8]);

  float mrow[4], lrow[4];
#pragma unroll
  for (int r = 0; r < 4; ++r) { mrow[r] = -INFINITY; lrow[r] = 0.0f; }
  f32x4 accO[8] = {};

  int s_lo = q0 - (WIN - 1);
  if (s_lo < 0) s_lo = 0;
  s_lo &= ~31;
  const float scale = 0.08838834764831845f;  // 1/sqrt(128)

  for (int s0 = s_lo; s0 < q0 + 64; s0 += 32) {
    // stage K (row-major) and V (transposed)
#pragma unroll
    for (int i = 0; i < 2; ++i) {
      int slot = tid + i * 256;
      int kr = slot >> 4, kc = (slot & 15) * 8;
      *reinterpret_cast<bf16x8*>(&lK[kr][kc]) =
          *reinterpret_cast<const bf16x8*>(&Kb[(size_t)(s0 + kr) * HD + kc]);
      int vr = slot & 31, vc = (slot >> 5) * 8;
      bf16x8 vv = *reinterpret_cast<const bf16x8*>(&Vb[(size_t)(s0 + vr) * HD + vc]);
#pragma unroll
      for (int j = 0; j < 8; ++j) lVt[vc + j][vr] = vv[j];
    }
    __syncthreads();

    // QK^T: 16 q x 32 s
    f32x4 accS[2] = {};
#pragma unroll
    for (int sb = 0; sb < 2; ++sb) {
#pragma unroll
      for (int dblk = 0; dblk < 4; ++dblk) {
        bf16x8 bk = *reinterpret_cast<const bf16x8*>(&lK[sb * 16 + l16][dblk * 32 + lhi * 8]);
        accS[sb] = __builtin_amdgcn_mfma_f32_16x16x32_bf16(aq[dblk], bk, accS[sb], 0, 0, 0);
      }
    }

    // mask + online softmax (row r of this lane group = qw + lhi*4 + r)
    float p0s[4], p1s[4];
#pragma unroll
    for (int r = 0; r < 4; ++r) {
      int qrow = qw + lhi * 4 + r;
      int sc0 = s0 + l16, sc1 = s0 + 16 + l16;
      float v0 = accS[0][r] * scale;
      float v1 = accS[1][r] * scale;
      bool ok0 = (sc0 <= qrow) && (qrow - sc0 < WIN);
      bool ok1 = (sc1 <= qrow) && (qrow - sc1 < WIN);
      v0 = ok0 ? v0 : -INFINITY;
      v1 = ok1 ? v1 : -INFINITY;
      float tmax = fmaxf(v0, v1);
#pragma unroll
      for (int off = 1; off < 16; off <<= 1) tmax = fmaxf(tmax, __shfl_xor(tmax, off, 64));
      float mnew = fmaxf(mrow[r], tmax);
      float msafe = (mnew == -INFINITY) ? 0.0f : mnew;
      float corr = (mrow[r] == mnew) ? 1.0f : __expf(mrow[r] - mnew);
      float p0 = __expf(v0 - msafe);
      float p1 = __expf(v1 - msafe);
      float psum = p0 + p1;
#pragma unroll
      for (int off = 1; off < 16; off <<= 1) psum += __shfl_xor(psum, off, 64);
      lrow[r] = lrow[r] * corr + psum;
      mrow[r] = mnew;
#pragma unroll
      for (int ni = 0; ni < 8; ++ni) accO[ni][r] *= corr;
      p0s[r] = p0;
      p1s[r] = p1;
    }

    // P (C/D layout) -> LDS -> A-operand layout
#pragma unroll
    for (int r = 0; r < 4; ++r) {
      lP[wid][lhi * 4 + r][l16] = (__bf16)p0s[r];
      lP[wid][lhi * 4 + r][16 + l16] = (__bf16)p1s[r];
    }
    bf16x8 ap = *reinterpret_cast<const bf16x8*>(&lP[wid][l16][lhi * 8]);
#pragma unroll
    for (int ni = 0; ni < 8; ++ni) {
      bf16x8 bv = *reinterpret_cast<const bf16x8*>(&lVt[ni * 16 + l16][lhi * 8]);
      accO[ni] = __builtin_amdgcn_mfma_f32_16x16x32_bf16(ap, bv, accO[ni], 0, 0, 0);
    }
    __syncthreads();
  }

  float invl[4];
#pragma unroll
  for (int r = 0; r < 4; ++r) invl[r] = 1.0f / lrow[r];
#pragma unroll
  for (int ni = 0; ni < 8; ++ni) {
#pragma unroll
    for (int r = 0; r < 4; ++r) {
      int row = qw + lhi * 4 + r;
      int d = ni * 16 + l16;
      Aout[((size_t)(b * TSEQ + row)) * CDIM + h * HD + d] = (__bf16)(accO[ni][r] * invl[r]);
    }
  }
}

// ---------------------------------------------------------------------------
// Output GEMM + residual: out f32 = x + A[4096][2048] @ wo (woT bf16 [N][K])
// ---------------------------------------------------------------------------
__global__ __launch_bounds__(256) void k_gemm_out(const __bf16* __restrict__ A,
                                                  const __bf16* __restrict__ woT,
                                                  const float* __restrict__ x,
                                                  float* __restrict__ out) {
  __shared__ __align__(16) __bf16 lA[128][40];
  __shared__ __align__(16) __bf16 lB[128][40];
  const int tid = threadIdx.x;
  const int lane = tid & 63;
  const int wid = tid >> 6;
  const int wrow = (wid >> 1) * 64, wcol = (wid & 1) * 64;
  const int l16 = lane & 15, lhi = lane >> 4;
  const int m0 = blockIdx.y * 128;
  const int n0 = blockIdx.x * 128;

  f32x4 acc[4][4] = {};

  for (int k0 = 0; k0 < CDIM; k0 += 32) {
#pragma unroll
    for (int i = 0; i < 2; ++i) {
      int slot = tid + i * 256;
      int r = slot >> 2, c = (slot & 3) * 8;
      *reinterpret_cast<bf16x8*>(&lA[r][c]) =
          *reinterpret_cast<const bf16x8*>(&A[(size_t)(m0 + r) * CDIM + k0 + c]);
      *reinterpret_cast<bf16x8*>(&lB[r][c]) =
          *reinterpret_cast<const bf16x8*>(&woT[(size_t)(n0 + r) * CDIM + k0 + c]);
    }
    __syncthreads();
    bf16x8 a[4], b[4];
#pragma unroll
    for (int mi = 0; mi < 4; ++mi)
      a[mi] = *reinterpret_cast<const bf16x8*>(&lA[wrow + mi * 16 + l16][lhi * 8]);
#pragma unroll
    for (int ni = 0; ni < 4; ++ni)
      b[ni] = *reinterpret_cast<const bf16x8*>(&lB[wcol + ni * 16 + l16][lhi * 8]);
#pragma unroll
    for (int mi = 0; mi < 4; ++mi)
#pragma unroll
      for (int ni = 0; ni < 4; ++ni)
        acc[mi][ni] = __builtin_amdgcn_mfma_f32_16x16x32_bf16(a[mi], b[ni], acc[mi][ni], 0, 0, 0);
    __syncthreads();
  }

#pragma unroll
  for (int mi = 0; mi < 4; ++mi) {
#pragma unroll
    for (int ni = 0; ni < 4; ++ni) {
#pragma unroll
      for (int r = 0; r < 4; ++r) {
        int row = m0 + wrow + mi * 16 + lhi * 4 + r;
        int col = n0 + wcol + ni * 16 + l16;
        size_t idx = (size_t)row * CDIM + col;
        out[idx] = x[idx] + acc[mi][ni][r];
      }
    }
  }
}

// ---------------------------------------------------------------------------
extern "C" void kernel_launch(void* const* d_in, const int* in_sizes, int n_in,
                              void* d_out, int out_size, void* d_ws, size_t ws_size,
                              hipStream_t stream) {
  const float* x = (const float*)d_in[0];
  const float* norm_w = (const float*)d_in[1];
  const float* wq = (const float*)d_in[2];
  const float* wk = (const float*)d_in[3];
  const float* wv = (const float*)d_in[4];
  const float* wo = (const float*)d_in[5];
  const float* rc = (const float*)d_in[6];
  const float* rs = (const float*)d_in[7];
  float* out = (float*)d_out;

  char* ws = (char*)d_ws;
  // workspace layout (bytes)
  __bf16* xn  = (__bf16*)(ws);              // 4096x2048 bf16 = 16.8MB (reused as attn_out)
  __bf16* wqT = (__bf16*)(ws + 16777216);   // 2048x2048 bf16
  __bf16* wkT = (__bf16*)(ws + 25165824);   // 512x2048
  __bf16* wvT = (__bf16*)(ws + 27262976);   // 512x2048
  __bf16* woT = (__bf16*)(ws + 29360128);   // 2048x2048
  __bf16* Qb  = (__bf16*)(ws + 37748736);   // 2x16x2048x128
  __bf16* Kb  = (__bf16*)(ws + 54525952);   // 2x4x2048x128
  __bf16* Vb  = (__bf16*)(ws + 58720256);   // 2x4x2048x128  (end 62914560)
  if (ws_size < 62914560) return;

  k_wtrans<<<dim3(32, 32), 256, 0, stream>>>(wq, wqT, 2048);
  k_wtrans<<<dim3(8, 32), 256, 0, stream>>>(wk, wkT, 512);
  k_wtrans<<<dim3(8, 32), 256, 0, stream>>>(wv, wvT, 512);
  k_wtrans<<<dim3(32, 32), 256, 0, stream>>>(wo, woT, 2048);
  k_rmsnorm<<<4096, 256, 0, stream>>>(x, norm_w, xn);
  k_gemm_qkv<<<dim3(24, 32), 256, 0, stream>>>(xn, wqT, wkT, wvT, Qb, Kb, Vb);
  k_rope<<<(BDIM * TSEQ * (NH + NKV)) / 4, 256, 0, stream>>>(Qb, Kb, rc, rs);
  k_attn<<<dim3(TSEQ / 64, BDIM * NH), 256, 0, stream>>>(Qb, Kb, Vb, xn);
  k_gemm_out<<<dim3(16, 32), 256, 0, stream>>>(xn, woT, x, out);
}